// Round 16
// baseline (356.354 us; speedup 1.0000x reference)
//
#include <hip/hip_runtime.h>
#include <hip/hip_bf16.h>

typedef __attribute__((ext_vector_type(8))) short short8;
typedef __attribute__((ext_vector_type(4))) float f32x4;

#define MFMA_B16(a, b, c) __builtin_amdgcn_mfma_f32_16x16x32_bf16((a), (b), (c), 0, 0, 0)

__device__ __forceinline__ float bf2f(unsigned short u) {
    union { unsigned int i; float f; } v; v.i = ((unsigned int)u) << 16; return v.f;
}
__device__ __forceinline__ unsigned short f2bf(float f) {
    union { float f; unsigned int i; } v; v.f = f;
    unsigned int r = v.i + 0x7fffu + ((v.i >> 16) & 1u);
    return (unsigned short)(r >> 16);
}
// fast HW transcendentals; gate scales folded into weights at convert time.
__device__ __forceinline__ float rcp_f(float x) { return __builtin_amdgcn_rcpf(x); }
__device__ __forceinline__ float sigm_pre(float x) {      // x = -log2(e)*(...)
    return rcp_f(1.0f + __builtin_amdgcn_exp2f(x));
}
__device__ __forceinline__ float tanh_pre(float x) {      // x = 2*log2(e)*(...)
    return 1.0f - 2.0f * rcp_f(__builtin_amdgcn_exp2f(x) + 1.0f);
}

__device__ __forceinline__ bool probe_bf16(const unsigned short* p, int tid, int* s_cnt) {
    if (tid == 0) *s_cnt = 0;
    __syncthreads();
    unsigned short s = p[tid & 255];
    int e = (s >> 7) & 0xFF;
    if (tid < 256 && e >= 117 && e <= 137) atomicAdd(s_cnt, 1);
    __syncthreads();
    return *s_cnt >= 200;
}

// ---------------------------------------------------------------------------
// Convert 20 weight/bias tensors to a bf16 arena with gate scale folding.
// GRU tensors (0..15, last dim 192): cols 0..127 x -log2(e); cols 128..191
// x 2*log2(e) for d2/tanh (8..15), x1 for d1/relu (0..7). Head unscaled.
// ---------------------------------------------------------------------------
struct WArgs {
    const void* src[20];
    int off[21];
};

__global__ __launch_bounds__(256)
void convert_w(WArgs a, unsigned short* __restrict__ arena,
               const unsigned short* __restrict__ probe)
{
    __shared__ int cnt;
    const bool bf = probe_bf16(probe, threadIdx.x, &cnt);
    const int total = a.off[20];
    for (int i = blockIdx.x * 256 + threadIdx.x; i < total; i += gridDim.x * 256) {
        int t = 0;
        while (t < 19 && i >= a.off[t + 1]) ++t;
        const int local = i - a.off[t];
        float v = bf ? bf2f(((const unsigned short*)a.src[t])[local])
                     : ((const float*)a.src[t])[local];
        if (t < 16) {
            const int col = local % 192;
            if (col < 128) v *= -1.4426950408889634f;
            else if (t >= 8) v *= 2.885390081777927f;
        }
        arena[i] = f2bf(v);
    }
}

// ---------------------------------------------------------------------------
// Layer 1 WAVE-AUTONOMOUS: one 64-lane wave owns a full 16-row recurrence
// (all 64 units, all 12 gate col-tiles in registers). NO barriers in the
// 72-step loop — h round-trips through wave-private LDS (in-order per wave).
// block = 64 threads; grid (bchunk/16, 2) = 512 single-wave blocks.
// ---------------------------------------------------------------------------
__global__ __launch_bounds__(64, 1)
void gru1_kernel(const void* __restrict__ X, const void* __restrict__ h0f,
                 const void* __restrict__ h0b, int cb, int bchunk,
                 const unsigned short* __restrict__ Wf, const unsigned short* __restrict__ Uf,
                 const unsigned short* __restrict__ bif, const unsigned short* __restrict__ brf,
                 const unsigned short* __restrict__ Wb, const unsigned short* __restrict__ Ub,
                 const unsigned short* __restrict__ bib, const unsigned short* __restrict__ brb,
                 unsigned short* __restrict__ seq)
{
    const int lane = threadIdx.x;        // 0..63
    const int q    = lane >> 4;
    const int ln   = lane & 15;
    const int dir  = blockIdx.y;
    const int lb0  = blockIdx.x * 16;
    const int gb0  = cb + lb0;

    const unsigned short* W  = dir ? Wb  : Wf;
    const unsigned short* U  = dir ? Ub  : Uf;
    const unsigned short* bi = dir ? bib : bif;
    const unsigned short* br = dir ? brb : brf;
    const void* h0 = dir ? h0b : h0f;

    __shared__ __align__(16) unsigned short hbuf[16][72];   // h bf16, wave-private
    __shared__ __align__(16) unsigned short Ax[2][16][40];  // x hi/lo (18 real)

    // wave-local dtype probe: 256 samples, 4 per lane, ballot-reduced
    int pc = 0;
#pragma unroll
    for (int j = 0; j < 4; ++j) {
        unsigned short s = ((const unsigned short*)X)[lane * 4 + j];
        int e = (s >> 7) & 0xFF;
        pc += (int)__popcll(__ballot(e >= 117 && e <= 137));
    }
    const bool xbf = pc >= 200;

    // zero Ax (cols >=18 must stay 0)
    {
        unsigned short* p = &Ax[0][0][0];
        for (int i = lane; i < 2 * 16 * 40; i += 64) p[i] = 0;
    }

    // x(t=0): 144 elems, hi/lo split
    {
        const int tx0 = dir ? 71 : 0;
        for (int e = lane; e < 144; e += 64) {
            int r = e / 9, k = e - 9 * r;
            size_t idx = ((size_t)(gb0 + r) * 72 + tx0) * 9 + k;
            unsigned short hv, lv;
            if (xbf) { hv = ((const unsigned short*)X)[idx]; lv = 0; }
            else { float v = ((const float*)X)[idx]; hv = f2bf(v); lv = f2bf(v - bf2f(hv)); }
            Ax[0][r][2 * k]     = hv;
            Ax[0][r][2 * k + 1] = lv;
        }
    }

    // ALL 12 gate col-tiles in registers. tile ct: gcol = ct*16 + ln
    // (ct 0..3 = z, 4..7 = r, 8..11 = candidate). Arena is pre-scaled.
    short8 bU[12][2];   // recurrent K=64
    short8 bW[12];      // x-projection K=32 (18 real hi/lo)
#pragma unroll
    for (int ct = 0; ct < 12; ++ct) {
        const int gcol = ct * 16 + ln;
#pragma unroll
        for (int ks = 0; ks < 2; ++ks) {
            short8 f;
#pragma unroll
            for (int j = 0; j < 8; ++j) {
                int kp = ks * 32 + q * 8 + j;
                f[j] = (short)U[(size_t)kp * 192 + gcol];
            }
            bU[ct][ks] = f;
        }
        short8 fw;
#pragma unroll
        for (int j = 0; j < 8; ++j) {
            int kp = q * 8 + j;
            fw[j] = (kp < 18) ? (short)W[(size_t)(kp >> 1) * 192 + gcol] : (short)0;
        }
        bW[ct] = fw;
    }

    // per-lane biases for its 4 unit-groups (u = 16*t4 + ln)
    float bzv[4], brv[4], bxv[4], bhv[4];
#pragma unroll
    for (int t4 = 0; t4 < 4; ++t4) {
        const int u = t4 * 16 + ln;
        bzv[t4] = bf2f(bi[u])        + bf2f(br[u]);        // pre-scaled
        brv[t4] = bf2f(bi[64 + u])   + bf2f(br[64 + u]);   // pre-scaled
        bxv[t4] = bf2f(bi[128 + u]);                       // relu: unscaled
        bhv[t4] = bf2f(br[128 + u]);
    }

    // h0 init: lane owns (rows q*4+i, units 16*t4+ln)
    float hreg[16];
#pragma unroll
    for (int t4 = 0; t4 < 4; ++t4) {
#pragma unroll
        for (int i = 0; i < 4; ++i) {
            const int row = q * 4 + i;
            const int u   = t4 * 16 + ln;
            float hv = xbf ? bf2f(((const unsigned short*)h0)[(size_t)(gb0 + row) * 64 + u])
                           : ((const float*)h0)[(size_t)(gb0 + row) * 64 + u];
            hreg[t4 * 4 + i] = hv;
            hbuf[row][u] = f2bf(hv);
        }
    }

    // depth-2 x pipeline: preload x(1)
    unsigned short chh[3] = {0, 0, 0}, cll[3] = {0, 0, 0};
    {
        const int tx = dir ? 70 : 1;
#pragma unroll
        for (int j = 0; j < 3; ++j) {
            int e = lane + 64 * j;
            if (e < 144) {
                int r = e / 9, k = e - 9 * r; (void)k;
                size_t idx = ((size_t)(gb0 + r) * 72 + tx) * 9 + (e - 9 * r);
                if (xbf) { chh[j] = ((const unsigned short*)X)[idx]; cll[j] = 0; }
                else { float v = ((const float*)X)[idx]; chh[j] = f2bf(v); cll[j] = f2bf(v - bf2f(chh[j])); }
            }
        }
    }
    __syncthreads();   // single wave: cheap; orders init LDS writes

    for (int t = 0; t < 72; ++t) {
        const int cur = t & 1, nb = cur ^ 1;

        // prefetch x(t+2)
        unsigned short fhh[3] = {0, 0, 0}, fll[3] = {0, 0, 0};
        if (t < 70) {
            const int tx = dir ? (69 - t) : (t + 2);
#pragma unroll
            for (int j = 0; j < 3; ++j) {
                int e = lane + 64 * j;
                if (e < 144) {
                    int r = e / 9;
                    size_t idx = ((size_t)(gb0 + r) * 72 + tx) * 9 + (e - 9 * r);
                    if (xbf) { fhh[j] = ((const unsigned short*)X)[idx]; fll[j] = 0; }
                    else { float v = ((const float*)X)[idx]; fhh[j] = f2bf(v); fll[j] = f2bf(v - bf2f(fhh[j])); }
                }
            }
        }

        // A-frags: h(t) and x(t)
        short8 a0 = *(const short8*)&hbuf[ln][q * 8];
        short8 a1 = *(const short8*)&hbuf[ln][32 + q * 8];
        short8 ax = *(const short8*)&Ax[cur][ln][q * 8];

        // 36 MFMAs: 12 independent tiles
        f32x4 gz[4], gr[4], ghx[4], ghr[4];
#pragma unroll
        for (int t4 = 0; t4 < 4; ++t4) {
            f32x4 Cz  = {bzv[t4], bzv[t4], bzv[t4], bzv[t4]};
            f32x4 Cr  = {brv[t4], brv[t4], brv[t4], brv[t4]};
            f32x4 Chx = {bxv[t4], bxv[t4], bxv[t4], bxv[t4]};
            f32x4 Chr = {bhv[t4], bhv[t4], bhv[t4], bhv[t4]};
            f32x4 z = MFMA_B16(ax, bW[t4], Cz);
            z = MFMA_B16(a0, bU[t4][0], z);
            z = MFMA_B16(a1, bU[t4][1], z);
            gz[t4] = z;
            f32x4 r = MFMA_B16(ax, bW[4 + t4], Cr);
            r = MFMA_B16(a0, bU[4 + t4][0], r);
            r = MFMA_B16(a1, bU[4 + t4][1], r);
            gr[t4] = r;
            ghx[t4] = MFMA_B16(ax, bW[8 + t4], Chx);
            f32x4 hr = MFMA_B16(a0, bU[8 + t4][0], Chr);
            hr = MFMA_B16(a1, bU[8 + t4][1], hr);
            ghr[t4] = hr;
        }

        // gates: 16 elements/lane (rows q*4+i, units 16*t4+ln); scatter to hbuf
#pragma unroll
        for (int t4 = 0; t4 < 4; ++t4) {
#pragma unroll
            for (int i = 0; i < 4; ++i) {
                float z = sigm_pre(gz[t4][i]);
                float r = sigm_pre(gr[t4][i]);
                float hh = fmaxf(ghx[t4][i] + r * ghr[t4][i], 0.0f);
                float ho = hreg[t4 * 4 + i];
                float hn = hh + z * (ho - hh);
                hreg[t4 * 4 + i] = hn;
                hbuf[q * 4 + i][t4 * 16 + ln] = f2bf(hn);
            }
        }

        // store h(t+1) = state after consuming x(t) -> seq[t] (fwd) / seq[71-t]
        {
            const int tw = dir ? (71 - t) : t;
#pragma unroll
            for (int j = 0; j < 2; ++j) {
                int chunk = lane + 64 * j;
                int row = chunk >> 3, c = chunk & 7;
                int4 v = *(const int4*)&hbuf[row][c * 8];
                *(int4*)(seq + ((size_t)tw * bchunk + lb0 + row) * 128 + dir * 64 + c * 8) = v;
            }
        }

        // stage x(t+1)
        if (t < 71) {
#pragma unroll
            for (int j = 0; j < 3; ++j) {
                int e = lane + 64 * j;
                if (e < 144) {
                    int r = e / 9, k = e - 9 * r;
                    Ax[nb][r][2 * k]     = chh[j];
                    Ax[nb][r][2 * k + 1] = cll[j];
                }
            }
        }
#pragma unroll
        for (int j = 0; j < 3; ++j) { chh[j] = fhh[j]; cll[j] = fll[j]; }
    }
}

// ---------------------------------------------------------------------------
// Layer 2: bidirectional GRU(64), tanh (pre-scaled). Arena weights; seq
// A-frags direct from global, depth-2 prefetch; projections pre-barrier.
// grid (bchunk/16, 2), block 256.  [R13 known-good]
// ---------------------------------------------------------------------------
__global__ __launch_bounds__(256, 1)
void gru2_kernel(const unsigned short* __restrict__ seq, int cb, int bchunk,
                 const unsigned short* __restrict__ W2f, const unsigned short* __restrict__ U2f,
                 const unsigned short* __restrict__ bi2f, const unsigned short* __restrict__ br2f,
                 const unsigned short* __restrict__ W2b, const unsigned short* __restrict__ U2b,
                 const unsigned short* __restrict__ bi2b, const unsigned short* __restrict__ br2b,
                 float* __restrict__ feat)
{
    const int tid  = threadIdx.x;
    const int lane = tid & 63;
    const int wv   = tid >> 6;
    const int q    = lane >> 4;
    const int ln   = lane & 15;
    const int dir  = blockIdx.y;
    const int lb0  = blockIdx.x * 16;
    const int gb0  = cb + lb0;
    const int u    = wv * 16 + ln;

    const unsigned short* W  = dir ? W2b  : W2f;
    const unsigned short* U  = dir ? U2b  : U2f;
    const unsigned short* bi = dir ? bi2b : bi2f;
    const unsigned short* br = dir ? br2b : br2f;

    __shared__ __align__(16) unsigned short Ah[2][16][72];

    {
        unsigned short* p = &Ah[0][0][0];
        for (int i = tid; i < 16 * 72; i += 256) p[i] = 0;
    }

    const long long tstride = (long long)bchunk * 128 * (dir ? -1 : 1);
    const unsigned short* sptr0 = seq + ((size_t)(lb0 + ln)) * 128 + q * 8
                                + (dir ? 71ll * bchunk * 128 : 0);

    short8 bU[3][2];
    short8 bV[3][4];
#pragma unroll
    for (int g = 0; g < 3; ++g) {
        const int col = g * 64 + u;
#pragma unroll
        for (int ks = 0; ks < 2; ++ks) {
            short8 f;
#pragma unroll
            for (int j = 0; j < 8; ++j) {
                int kp = ks * 32 + q * 8 + j;
                f[j] = (short)U[(size_t)kp * 192 + col];
            }
            bU[g][ks] = f;
        }
#pragma unroll
        for (int ks = 0; ks < 4; ++ks) {
            short8 fv;
#pragma unroll
            for (int j = 0; j < 8; ++j) {
                int kp = ks * 32 + q * 8 + j;
                fv[j] = (short)W[(size_t)kp * 192 + col];
            }
            bV[g][ks] = fv;
        }
    }

    const float bz  = bf2f(bi[u])       + bf2f(br[u]);
    const float brg = bf2f(bi[64 + u])  + bf2f(br[64 + u]);
    const float bih = bf2f(bi[128 + u]);
    const float brh = bf2f(br[128 + u]);
    const f32x4 Cz  = {bz,  bz,  bz,  bz};
    const f32x4 Cr  = {brg, brg, brg, brg};
    const f32x4 Chx = {bih, bih, bih, bih};
    const f32x4 Chr = {brh, brh, brh, brh};

    float hreg[4];
#pragma unroll
    for (int i = 0; i < 4; ++i) hreg[i] = 0.0f;

    f32x4 P0, P1, P2;
    {
        const unsigned short* sp = sptr0;
        short8 s0 = *(const short8*)(sp);
        short8 s1 = *(const short8*)(sp + 32);
        short8 s2 = *(const short8*)(sp + 64);
        short8 s3 = *(const short8*)(sp + 96);
        P0 = MFMA_B16(s0, bV[0][0], Cz);
        P0 = MFMA_B16(s1, bV[0][1], P0);
        P0 = MFMA_B16(s2, bV[0][2], P0);
        P0 = MFMA_B16(s3, bV[0][3], P0);
        P1 = MFMA_B16(s0, bV[1][0], Cr);
        P1 = MFMA_B16(s1, bV[1][1], P1);
        P1 = MFMA_B16(s2, bV[1][2], P1);
        P1 = MFMA_B16(s3, bV[1][3], P1);
        P2 = MFMA_B16(s0, bV[2][0], Chx);
        P2 = MFMA_B16(s1, bV[2][1], P2);
        P2 = MFMA_B16(s2, bV[2][2], P2);
        P2 = MFMA_B16(s3, bV[2][3], P2);
    }
    short8 c0, c1, c2, c3;
    {
        const unsigned short* sp = sptr0 + tstride;
        c0 = *(const short8*)(sp);
        c1 = *(const short8*)(sp + 32);
        c2 = *(const short8*)(sp + 64);
        c3 = *(const short8*)(sp + 96);
    }
    __syncthreads();

#pragma unroll 2
    for (int t = 0; t < 72; ++t) {
        const int cur = t & 1, nb = cur ^ 1;

        short8 f0, f1, f2, f3;
        const bool pf2 = (t < 70);
        if (pf2) {
            const unsigned short* sp = sptr0 + (long long)(t + 2) * tstride;
            f0 = *(const short8*)(sp);
            f1 = *(const short8*)(sp + 32);
            f2 = *(const short8*)(sp + 64);
            f3 = *(const short8*)(sp + 96);
        }

        const unsigned short* ap = &Ah[cur][ln][0];
        short8 a0 = *(const short8*)(ap + q * 8);
        short8 a1 = *(const short8*)(ap + 32 + q * 8);
        f32x4 az  = MFMA_B16(a0, bU[0][0], P0);
        az        = MFMA_B16(a1, bU[0][1], az);
        f32x4 ar  = MFMA_B16(a0, bU[1][0], P1);
        ar        = MFMA_B16(a1, bU[1][1], ar);
        f32x4 ahr = MFMA_B16(a0, bU[2][0], Chr);
        ahr       = MFMA_B16(a1, bU[2][1], ahr);
        f32x4 ahx = P2;

#pragma unroll
        for (int i = 0; i < 4; ++i) {
            const int m = q * 4 + i;
            float z = sigm_pre(az[i]);
            float r = sigm_pre(ar[i]);
            float pre = ahx[i] + r * ahr[i];
            float hh = tanh_pre(pre);
            float hn = hh + z * (hreg[i] - hh);
            hreg[i] = hn;
            Ah[nb][m][u] = f2bf(hn);
        }

        if (t < 71) {
            P0 = MFMA_B16(c0, bV[0][0], Cz);
            P0 = MFMA_B16(c1, bV[0][1], P0);
            P0 = MFMA_B16(c2, bV[0][2], P0);
            P0 = MFMA_B16(c3, bV[0][3], P0);
            P1 = MFMA_B16(c0, bV[1][0], Cr);
            P1 = MFMA_B16(c1, bV[1][1], P1);
            P1 = MFMA_B16(c2, bV[1][2], P1);
            P1 = MFMA_B16(c3, bV[1][3], P1);
            P2 = MFMA_B16(c0, bV[2][0], Chx);
            P2 = MFMA_B16(c1, bV[2][1], P2);
            P2 = MFMA_B16(c2, bV[2][2], P2);
            P2 = MFMA_B16(c3, bV[2][3], P2);
        }
        if (pf2) { c0 = f0; c1 = f1; c2 = f2; c3 = f3; }
        __syncthreads();
    }

#pragma unroll
    for (int i = 0; i < 4; ++i) {
        const int m = q * 4 + i;
        feat[(size_t)(gb0 + m) * 128 + dir * 64 + u] = hreg[i];
    }
}

// ---------------------------------------------------------------------------
__global__ __launch_bounds__(256, 1)
void head_kernel(const float* __restrict__ feat,
                 const unsigned short* __restrict__ dW, const unsigned short* __restrict__ db,
                 const unsigned short* __restrict__ oW, const unsigned short* __restrict__ ob,
                 float* __restrict__ out)
{
    const int tid = threadIdx.x;
    const int b0  = blockIdx.x * 16;

    __shared__ __align__(16) unsigned short Wl[128][136];
    __shared__ __align__(16) float fs[16][128];
    __shared__ __align__(16) float hs[16][136];
    __shared__ __align__(16) float ls[16][32];

    for (int i = tid; i < 2048; i += 256) {
        const int k = i >> 4;
        const int c = (i & 15) * 8;
        *(int4*)&Wl[k][c] = *(const int4*)(dW + (size_t)k * 128 + c);
    }
    {
        const float4* src = (const float4*)(feat + (size_t)b0 * 128);
        float4* dst = (float4*)&fs[0][0];
        for (int i = tid; i < 512; i += 256) dst[i] = src[i];
    }
    __syncthreads();

    {
        const int row = tid >> 4;
        const int j0  = (tid & 15) * 8;
        float acc[8];
#pragma unroll
        for (int jj = 0; jj < 8; ++jj) acc[jj] = bf2f(db[j0 + jj]);
        for (int k = 0; k < 128; ++k) {
            float f = fs[row][k];
            short8 w = *(const short8*)&Wl[k][j0];
#pragma unroll
            for (int jj = 0; jj < 8; ++jj)
                acc[jj] += f * bf2f((unsigned short)w[jj]);
        }
#pragma unroll
        for (int jj = 0; jj < 8; ++jj) hs[row][j0 + jj] = fmaxf(acc[jj], 0.0f);
    }
    __syncthreads();

    for (int e = tid; e < 16 * 24; e += 256) {
        const int row = e / 24, l = e - 24 * row;
        float acc = bf2f(ob[l]);
        for (int k = 0; k < 128; ++k)
            acc += hs[row][k] * bf2f(oW[(size_t)k * 24 + l]);
        ls[row][l] = acc;
    }
    __syncthreads();

    for (int e = tid; e < 16 * 24; e += 256) {
        const int row = e / 24, l = e - 24 * row;
        float mx = ls[row][0];
#pragma unroll
        for (int k = 1; k < 24; ++k) mx = fmaxf(mx, ls[row][k]);
        float s = 0.0f;
#pragma unroll
        for (int k = 0; k < 24; ++k) s += __expf(ls[row][k] - mx);
        float v = __expf(ls[row][l] - mx) * rcp_f(s);
        out[(size_t)(b0 + row) * 24 + l] = v;
    }
}

// ---------------------------------------------------------------------------
extern "C" void kernel_launch(void* const* d_in, const int* in_sizes, int n_in,
                              void* d_out, int out_size, void* d_ws, size_t ws_size,
                              hipStream_t stream) {
    (void)in_sizes; (void)n_in; (void)out_size;

    static const int wc[20] = {
        1728, 12288, 192, 192,
        1728, 12288, 192, 192,
        24576, 12288, 192, 192,
        24576, 12288, 192, 192,
        16384, 128,
        3072, 24
    };

    WArgs a;
    int off = 0;
    for (int t = 0; t < 20; ++t) {
        a.src[t] = d_in[t + 3];
        a.off[t] = off;
        off += wc[t];
    }
    a.off[20] = off;

    const unsigned long long arena_bytes = 245952ull;
    const unsigned long long feat_bytes  = 4096ull * 128ull * 4ull;
    const unsigned long long seq_full    = 72ull * 4096ull * 128ull * 2ull;
    const unsigned long long fixed       = arena_bytes + feat_bytes;

    int nc = 32;
    for (int c = 1; c <= 32; c *= 2) {
        if (fixed + seq_full / (unsigned long long)c <= (unsigned long long)ws_size) { nc = c; break; }
    }
    const int bchunk = 4096 / nc;

    unsigned short* arena = (unsigned short*)d_ws;
    float* feat           = (float*)((char*)d_ws + arena_bytes);
    unsigned short* seq   = (unsigned short*)((char*)d_ws + fixed);

    convert_w<<<128, 256, 0, stream>>>(a, arena, (const unsigned short*)d_in[0]);

    const unsigned short* d1fW = arena + a.off[0];
    const unsigned short* d1fU = arena + a.off[1];
    const unsigned short* d1fbi= arena + a.off[2];
    const unsigned short* d1fbr= arena + a.off[3];
    const unsigned short* d1bW = arena + a.off[4];
    const unsigned short* d1bU = arena + a.off[5];
    const unsigned short* d1bbi= arena + a.off[6];
    const unsigned short* d1bbr= arena + a.off[7];
    const unsigned short* d2fW = arena + a.off[8];
    const unsigned short* d2fU = arena + a.off[9];
    const unsigned short* d2fbi= arena + a.off[10];
    const unsigned short* d2fbr= arena + a.off[11];
    const unsigned short* d2bW = arena + a.off[12];
    const unsigned short* d2bU = arena + a.off[13];
    const unsigned short* d2bbi= arena + a.off[14];
    const unsigned short* d2bbr= arena + a.off[15];
    const unsigned short* dW   = arena + a.off[16];
    const unsigned short* db   = arena + a.off[17];
    const unsigned short* oW   = arena + a.off[18];
    const unsigned short* ob   = arena + a.off[19];

    for (int c = 0; c < nc; ++c) {
        const int cb = c * bchunk;
        gru1_kernel<<<dim3(bchunk / 16, 2), 64, 0, stream>>>(
            d_in[0], d_in[1], d_in[2], cb, bchunk,
            d1fW, d1fU, d1fbi, d1fbr, d1bW, d1bU, d1bbi, d1bbr, seq);
        gru2_kernel<<<dim3(bchunk / 16, 2), 256, 0, stream>>>(
            seq, cb, bchunk,
            d2fW, d2fU, d2fbi, d2fbr, d2bW, d2bU, d2bbi, d2bbr, feat);
    }
    head_kernel<<<256, 256, 0, stream>>>(
        feat, dW, db, oW, ob, (float*)d_out);
}

// Round 17
// 256.533 us; speedup vs baseline: 1.3891x; 1.3891x over previous
//
#include <hip/hip_runtime.h>
#include <hip/hip_bf16.h>

typedef __attribute__((ext_vector_type(8))) short short8;
typedef __attribute__((ext_vector_type(4))) float f32x4;

#define MFMA_B16(a, b, c) __builtin_amdgcn_mfma_f32_16x16x32_bf16((a), (b), (c), 0, 0, 0)

__device__ __forceinline__ float bf2f(unsigned short u) {
    union { unsigned int i; float f; } v; v.i = ((unsigned int)u) << 16; return v.f;
}
__device__ __forceinline__ unsigned short f2bf(float f) {
    union { float f; unsigned int i; } v; v.f = f;
    unsigned int r = v.i + 0x7fffu + ((v.i >> 16) & 1u);
    return (unsigned short)(r >> 16);
}
// fast HW transcendentals (1 inst each). Gate scale constants are folded into
// the weights at convert time: z/r pre-acts arrive pre-multiplied by -log2(e),
// gru2 candidate pre-acts by 2*log2(e).
__device__ __forceinline__ float rcp_f(float x) { return __builtin_amdgcn_rcpf(x); }
__device__ __forceinline__ float sigm_pre(float x) {      // x = -log2(e)*(...)
    return rcp_f(1.0f + __builtin_amdgcn_exp2f(x));
}
__device__ __forceinline__ float tanh_pre(float x) {      // x = 2*log2(e)*(...)
    return 1.0f - 2.0f * rcp_f(__builtin_amdgcn_exp2f(x) + 1.0f);
}

// probe 256 shorts: bf16 vs fp32 discrimination (deterministic per call)
__device__ __forceinline__ bool probe_bf16(const unsigned short* p, int tid, int* s_cnt) {
    if (tid == 0) *s_cnt = 0;
    __syncthreads();
    unsigned short s = p[tid & 255];
    int e = (s >> 7) & 0xFF;
    if (tid < 256 && e >= 117 && e <= 137) atomicAdd(s_cnt, 1);
    __syncthreads();
    return *s_cnt >= 200;
}

// ---------------------------------------------------------------------------
// Convert 20 weight/bias tensors (NOT x, NOT h0) to a bf16 arena with gate
// scale folding. Tensors 0..15 are GRU (last dim 192): cols 0..127 (z,r gates)
// scaled by -log2(e); cols 128..191 scaled by 2*log2(e) for d2 (tanh) tensors
// (8..15), by 1 for d1 (relu) tensors (0..7). Tensors 16..19 (head) unscaled.
// ---------------------------------------------------------------------------
struct WArgs {
    const void* src[20];
    int off[21];
};

__global__ __launch_bounds__(256)
void convert_w(WArgs a, unsigned short* __restrict__ arena,
               const unsigned short* __restrict__ probe)
{
    __shared__ int cnt;
    const bool bf = probe_bf16(probe, threadIdx.x, &cnt);
    const int total = a.off[20];
    for (int i = blockIdx.x * 256 + threadIdx.x; i < total; i += gridDim.x * 256) {
        int t = 0;
        while (t < 19 && i >= a.off[t + 1]) ++t;
        const int local = i - a.off[t];
        float v = bf ? bf2f(((const unsigned short*)a.src[t])[local])
                     : ((const float*)a.src[t])[local];
        if (t < 16) {
            const int col = local % 192;
            if (col < 128) v *= -1.4426950408889634f;
            else if (t >= 8) v *= 2.885390081777927f;
        }
        arena[i] = f2bf(v);
    }
}

// ---------------------------------------------------------------------------
// Layer 1: bidirectional GRU(64), relu candidate. 16 rows/block, h bf16 K=64,
// x hi/lo bf16 K=32 via LDS, depth-2 x prefetch. h0 converted inline.
// grid: (bchunk/16, 2), block 256.
// ---------------------------------------------------------------------------
__global__ __launch_bounds__(256, 1)
void gru1_kernel(const void* __restrict__ X, const void* __restrict__ h0f,
                 const void* __restrict__ h0b, int cb, int bchunk,
                 const unsigned short* __restrict__ Wf, const unsigned short* __restrict__ Uf,
                 const unsigned short* __restrict__ bif, const unsigned short* __restrict__ brf,
                 const unsigned short* __restrict__ Wb, const unsigned short* __restrict__ Ub,
                 const unsigned short* __restrict__ bib, const unsigned short* __restrict__ brb,
                 unsigned short* __restrict__ seq)
{
    const int tid  = threadIdx.x;
    const int lane = tid & 63;
    const int wv   = tid >> 6;
    const int q    = lane >> 4;
    const int ln   = lane & 15;
    const int dir  = blockIdx.y;
    const int lb0  = blockIdx.x * 16;
    const int gb0  = cb + lb0;
    const int u    = wv * 16 + ln;

    const unsigned short* W  = dir ? Wb  : Wf;
    const unsigned short* U  = dir ? Ub  : Uf;
    const unsigned short* bi = dir ? bib : bif;
    const unsigned short* br = dir ? brb : brf;
    const void* h0 = dir ? h0b : h0f;

    __shared__ __align__(16) unsigned short Ah[2][16][72];
    __shared__ __align__(16) unsigned short Ax[2][16][40];
    __shared__ int s_cnt;

    const bool xbf = probe_bf16((const unsigned short*)X, tid, &s_cnt);

    {
        unsigned short* p = &Ax[0][0][0];
        for (int i = tid; i < 2 * 16 * 40; i += 256) p[i] = 0;
    }
    __syncthreads();

    {
        const int tx0 = dir ? 71 : 0;
        if (tid < 144) {
            int r = tid / 9, k = tid - 9 * r;
            size_t idx = ((size_t)(gb0 + r) * 72 + tx0) * 9 + k;
            unsigned short hv, lv;
            if (xbf) { hv = ((const unsigned short*)X)[idx]; lv = 0; }
            else { float v = ((const float*)X)[idx]; hv = f2bf(v); lv = f2bf(v - bf2f(hv)); }
            Ax[0][r][2 * k]     = hv;
            Ax[0][r][2 * k + 1] = lv;
        }
    }

    short8 bU[3][2];
    short8 bW[3];
#pragma unroll
    for (int g = 0; g < 3; ++g) {
        const int col = g * 64 + u;
#pragma unroll
        for (int ks = 0; ks < 2; ++ks) {
            short8 f;
#pragma unroll
            for (int j = 0; j < 8; ++j) {
                int kp = ks * 32 + q * 8 + j;
                f[j] = (short)U[(size_t)kp * 192 + col];
            }
            bU[g][ks] = f;
        }
        short8 fw;
#pragma unroll
        for (int j = 0; j < 8; ++j) {
            int kp = q * 8 + j;
            fw[j] = (kp < 18) ? (short)W[(size_t)(kp >> 1) * 192 + col] : (short)0;
        }
        bW[g] = fw;
    }

    const float bz  = bf2f(bi[u])       + bf2f(br[u]);        // pre-scaled
    const float brg = bf2f(bi[64 + u])  + bf2f(br[64 + u]);   // pre-scaled
    const float bih = bf2f(bi[128 + u]);                      // unscaled (relu)
    const float brh = bf2f(br[128 + u]);
    const f32x4 Cz  = {bz,  bz,  bz,  bz};
    const f32x4 Cr  = {brg, brg, brg, brg};
    const f32x4 Chx = {bih, bih, bih, bih};
    const f32x4 Chr = {brh, brh, brh, brh};

    float hreg[4];
#pragma unroll
    for (int i = 0; i < 4; ++i) {
        int m = q * 4 + i;
        size_t idx = (size_t)(gb0 + m) * 64 + u;
        float hv = xbf ? bf2f(((const unsigned short*)h0)[idx])
                       : ((const float*)h0)[idx];
        hreg[i] = hv;
        Ah[0][m][u] = f2bf(hv);
    }

    const int r2 = tid >> 3, c2 = tid & 7;
    const int r0x = tid / 9, k0x = tid - 9 * r0x;

    // depth-2 x pipeline: ch/cl hold x(t+1); preload x(1)
    unsigned short ch = 0, cl = 0;
    if (tid < 144) {
        const int tx = dir ? 70 : 1;
        size_t idx = ((size_t)(gb0 + r0x) * 72 + tx) * 9 + k0x;
        if (xbf) { ch = ((const unsigned short*)X)[idx]; cl = 0; }
        else { float v = ((const float*)X)[idx]; ch = f2bf(v); cl = f2bf(v - bf2f(ch)); }
    }
    __syncthreads();

#pragma unroll 2
    for (int t = 0; t < 72; ++t) {
        const int cur = t & 1, nb = cur ^ 1;

        unsigned short fh = 0, fl = 0;
        if (t < 70 && tid < 144) {
            const int tx = dir ? (69 - t) : (t + 2);
            size_t idx = ((size_t)(gb0 + r0x) * 72 + tx) * 9 + k0x;
            if (xbf) { fh = ((const unsigned short*)X)[idx]; fl = 0; }
            else { float v = ((const float*)X)[idx]; fh = f2bf(v); fl = f2bf(v - bf2f(fh)); }
        }

        if (t > 0 && tid < 128) {
            const int tw = dir ? (71 - (t - 1)) : (t - 1);
            int4 v = *(const int4*)&Ah[cur][r2][c2 * 8];
            *(int4*)(seq + ((size_t)tw * bchunk + lb0 + r2) * 128 + dir * 64 + c2 * 8) = v;
        }

        const unsigned short* ap = &Ah[cur][ln][0];
        short8 a0 = *(const short8*)(ap + q * 8);
        short8 a1 = *(const short8*)(ap + 32 + q * 8);
        short8 ax = *(const short8*)(&Ax[cur][ln][q * 8]);
        f32x4 az  = MFMA_B16(ax, bW[0], Cz);
        az        = MFMA_B16(a0, bU[0][0], az);
        az        = MFMA_B16(a1, bU[0][1], az);
        f32x4 ar  = MFMA_B16(ax, bW[1], Cr);
        ar        = MFMA_B16(a0, bU[1][0], ar);
        ar        = MFMA_B16(a1, bU[1][1], ar);
        f32x4 ahx = MFMA_B16(ax, bW[2], Chx);
        f32x4 ahr = MFMA_B16(a0, bU[2][0], Chr);
        ahr       = MFMA_B16(a1, bU[2][1], ahr);

#pragma unroll
        for (int i = 0; i < 4; ++i) {
            const int m = q * 4 + i;
            float z = sigm_pre(az[i]);
            float r = sigm_pre(ar[i]);
            float pre = ahx[i] + r * ahr[i];
            float hh = fmaxf(pre, 0.0f);
            float hn = hh + z * (hreg[i] - hh);
            hreg[i] = hn;
            Ah[nb][m][u] = f2bf(hn);
        }

        if (t < 71 && tid < 144) {
            Ax[nb][r0x][2 * k0x]     = ch;
            Ax[nb][r0x][2 * k0x + 1] = cl;
        }
        ch = fh; cl = fl;
        __syncthreads();
    }

    if (tid < 128) {
        const int tw = dir ? 0 : 71;
        int4 v = *(const int4*)&Ah[0][r2][c2 * 8];
        *(int4*)(seq + ((size_t)tw * bchunk + lb0 + r2) * 128 + dir * 64 + c2 * 8) = v;
    }
}

// ---------------------------------------------------------------------------
// Layer 2: bidirectional GRU(64), tanh (pre-scaled candidate). Per-lane seq
// A-frags direct from global, depth-2 prefetch; 12 projection MFMAs
// pre-barrier, 6 recurrent + gates post-barrier. grid (bchunk/16, 2).
// ---------------------------------------------------------------------------
__global__ __launch_bounds__(256, 1)
void gru2_kernel(const unsigned short* __restrict__ seq, int cb, int bchunk,
                 const unsigned short* __restrict__ W2f, const unsigned short* __restrict__ U2f,
                 const unsigned short* __restrict__ bi2f, const unsigned short* __restrict__ br2f,
                 const unsigned short* __restrict__ W2b, const unsigned short* __restrict__ U2b,
                 const unsigned short* __restrict__ bi2b, const unsigned short* __restrict__ br2b,
                 float* __restrict__ feat)
{
    const int tid  = threadIdx.x;
    const int lane = tid & 63;
    const int wv   = tid >> 6;
    const int q    = lane >> 4;
    const int ln   = lane & 15;
    const int dir  = blockIdx.y;
    const int lb0  = blockIdx.x * 16;
    const int gb0  = cb + lb0;
    const int u    = wv * 16 + ln;

    const unsigned short* W  = dir ? W2b  : W2f;
    const unsigned short* U  = dir ? U2b  : U2f;
    const unsigned short* bi = dir ? bi2b : bi2f;
    const unsigned short* br = dir ? br2b : br2f;

    __shared__ __align__(16) unsigned short Ah[2][16][72];

    {
        unsigned short* p = &Ah[0][0][0];
        for (int i = tid; i < 16 * 72; i += 256) p[i] = 0;
    }

    const long long tstride = (long long)bchunk * 128 * (dir ? -1 : 1);
    const unsigned short* sptr0 = seq + ((size_t)(lb0 + ln)) * 128 + q * 8
                                + (dir ? 71ll * bchunk * 128 : 0);

    short8 bU[3][2];
    short8 bV[3][4];
#pragma unroll
    for (int g = 0; g < 3; ++g) {
        const int col = g * 64 + u;
#pragma unroll
        for (int ks = 0; ks < 2; ++ks) {
            short8 f;
#pragma unroll
            for (int j = 0; j < 8; ++j) {
                int kp = ks * 32 + q * 8 + j;
                f[j] = (short)U[(size_t)kp * 192 + col];
            }
            bU[g][ks] = f;
        }
#pragma unroll
        for (int ks = 0; ks < 4; ++ks) {
            short8 fv;
#pragma unroll
            for (int j = 0; j < 8; ++j) {
                int kp = ks * 32 + q * 8 + j;
                fv[j] = (short)W[(size_t)kp * 192 + col];
            }
            bV[g][ks] = fv;
        }
    }

    const float bz  = bf2f(bi[u])       + bf2f(br[u]);
    const float brg = bf2f(bi[64 + u])  + bf2f(br[64 + u]);
    const float bih = bf2f(bi[128 + u]);
    const float brh = bf2f(br[128 + u]);
    const f32x4 Cz  = {bz,  bz,  bz,  bz};
    const f32x4 Cr  = {brg, brg, brg, brg};
    const f32x4 Chx = {bih, bih, bih, bih};
    const f32x4 Chr = {brh, brh, brh, brh};

    float hreg[4];
#pragma unroll
    for (int i = 0; i < 4; ++i) hreg[i] = 0.0f;

    f32x4 P0, P1, P2;
    {
        const unsigned short* sp = sptr0;
        short8 s0 = *(const short8*)(sp);
        short8 s1 = *(const short8*)(sp + 32);
        short8 s2 = *(const short8*)(sp + 64);
        short8 s3 = *(const short8*)(sp + 96);
        P0 = MFMA_B16(s0, bV[0][0], Cz);
        P0 = MFMA_B16(s1, bV[0][1], P0);
        P0 = MFMA_B16(s2, bV[0][2], P0);
        P0 = MFMA_B16(s3, bV[0][3], P0);
        P1 = MFMA_B16(s0, bV[1][0], Cr);
        P1 = MFMA_B16(s1, bV[1][1], P1);
        P1 = MFMA_B16(s2, bV[1][2], P1);
        P1 = MFMA_B16(s3, bV[1][3], P1);
        P2 = MFMA_B16(s0, bV[2][0], Chx);
        P2 = MFMA_B16(s1, bV[2][1], P2);
        P2 = MFMA_B16(s2, bV[2][2], P2);
        P2 = MFMA_B16(s3, bV[2][3], P2);
    }
    short8 c0, c1, c2, c3;
    {
        const unsigned short* sp = sptr0 + tstride;
        c0 = *(const short8*)(sp);
        c1 = *(const short8*)(sp + 32);
        c2 = *(const short8*)(sp + 64);
        c3 = *(const short8*)(sp + 96);
    }
    __syncthreads();

#pragma unroll 2
    for (int t = 0; t < 72; ++t) {
        const int cur = t & 1, nb = cur ^ 1;

        short8 f0, f1, f2, f3;
        const bool pf2 = (t < 70);
        if (pf2) {
            const unsigned short* sp = sptr0 + (long long)(t + 2) * tstride;
            f0 = *(const short8*)(sp);
            f1 = *(const short8*)(sp + 32);
            f2 = *(const short8*)(sp + 64);
            f3 = *(const short8*)(sp + 96);
        }

        const unsigned short* ap = &Ah[cur][ln][0];
        short8 a0 = *(const short8*)(ap + q * 8);
        short8 a1 = *(const short8*)(ap + 32 + q * 8);
        f32x4 az  = MFMA_B16(a0, bU[0][0], P0);
        az        = MFMA_B16(a1, bU[0][1], az);
        f32x4 ar  = MFMA_B16(a0, bU[1][0], P1);
        ar        = MFMA_B16(a1, bU[1][1], ar);
        f32x4 ahr = MFMA_B16(a0, bU[2][0], Chr);
        ahr       = MFMA_B16(a1, bU[2][1], ahr);
        f32x4 ahx = P2;

#pragma unroll
        for (int i = 0; i < 4; ++i) {
            const int m = q * 4 + i;
            float z = sigm_pre(az[i]);
            float r = sigm_pre(ar[i]);
            float pre = ahx[i] + r * ahr[i];
            float hh = tanh_pre(pre);
            float hn = hh + z * (hreg[i] - hh);
            hreg[i] = hn;
            Ah[nb][m][u] = f2bf(hn);
        }

        if (t < 71) {
            P0 = MFMA_B16(c0, bV[0][0], Cz);
            P0 = MFMA_B16(c1, bV[0][1], P0);
            P0 = MFMA_B16(c2, bV[0][2], P0);
            P0 = MFMA_B16(c3, bV[0][3], P0);
            P1 = MFMA_B16(c0, bV[1][0], Cr);
            P1 = MFMA_B16(c1, bV[1][1], P1);
            P1 = MFMA_B16(c2, bV[1][2], P1);
            P1 = MFMA_B16(c3, bV[1][3], P1);
            P2 = MFMA_B16(c0, bV[2][0], Chx);
            P2 = MFMA_B16(c1, bV[2][1], P2);
            P2 = MFMA_B16(c2, bV[2][2], P2);
            P2 = MFMA_B16(c3, bV[2][3], P2);
        }
        if (pf2) { c0 = f0; c1 = f1; c2 = f2; c3 = f3; }
        __syncthreads();
    }

#pragma unroll
    for (int i = 0; i < 4; ++i) {
        const int m = q * 4 + i;
        feat[(size_t)(gb0 + m) * 128 + dir * 64 + u] = hreg[i];
    }
}

// ---------------------------------------------------------------------------
__global__ __launch_bounds__(256, 1)
void head_kernel(const float* __restrict__ feat,
                 const unsigned short* __restrict__ dW, const unsigned short* __restrict__ db,
                 const unsigned short* __restrict__ oW, const unsigned short* __restrict__ ob,
                 float* __restrict__ out)
{
    const int tid = threadIdx.x;
    const int b0  = blockIdx.x * 16;

    __shared__ __align__(16) unsigned short Wl[128][136];
    __shared__ __align__(16) float fs[16][128];
    __shared__ __align__(16) float hs[16][136];
    __shared__ __align__(16) float ls[16][32];

    for (int i = tid; i < 2048; i += 256) {
        const int k = i >> 4;
        const int c = (i & 15) * 8;
        *(int4*)&Wl[k][c] = *(const int4*)(dW + (size_t)k * 128 + c);
    }
    {
        const float4* src = (const float4*)(feat + (size_t)b0 * 128);
        float4* dst = (float4*)&fs[0][0];
        for (int i = tid; i < 512; i += 256) dst[i] = src[i];
    }
    __syncthreads();

    {
        const int row = tid >> 4;
        const int j0  = (tid & 15) * 8;
        float acc[8];
#pragma unroll
        for (int jj = 0; jj < 8; ++jj) acc[jj] = bf2f(db[j0 + jj]);
        for (int k = 0; k < 128; ++k) {
            float f = fs[row][k];
            short8 w = *(const short8*)&Wl[k][j0];
#pragma unroll
            for (int jj = 0; jj < 8; ++jj)
                acc[jj] += f * bf2f((unsigned short)w[jj]);
        }
#pragma unroll
        for (int jj = 0; jj < 8; ++jj) hs[row][j0 + jj] = fmaxf(acc[jj], 0.0f);
    }
    __syncthreads();

    for (int e = tid; e < 16 * 24; e += 256) {
        const int row = e / 24, l = e - 24 * row;
        float acc = bf2f(ob[l]);
        for (int k = 0; k < 128; ++k)
            acc += hs[row][k] * bf2f(oW[(size_t)k * 24 + l]);
        ls[row][l] = acc;
    }
    __syncthreads();

    for (int e = tid; e < 16 * 24; e += 256) {
        const int row = e / 24, l = e - 24 * row;
        float mx = ls[row][0];
#pragma unroll
        for (int k = 1; k < 24; ++k) mx = fmaxf(mx, ls[row][k]);
        float s = 0.0f;
#pragma unroll
        for (int k = 0; k < 24; ++k) s += __expf(ls[row][k] - mx);
        float v = __expf(ls[row][l] - mx) * rcp_f(s);
        out[(size_t)(b0 + row) * 24 + l] = v;
    }
}

// ---------------------------------------------------------------------------
extern "C" void kernel_launch(void* const* d_in, const int* in_sizes, int n_in,
                              void* d_out, int out_size, void* d_ws, size_t ws_size,
                              hipStream_t stream) {
    (void)in_sizes; (void)n_in; (void)out_size;

    // arena tensors: d_in[3..18] (GRU weights/biases), d_in[19..22] (head)
    static const int wc[20] = {
        1728, 12288, 192, 192,     // d1f W,U,bi,br   (t 0..3)
        1728, 12288, 192, 192,     // d1b             (t 4..7)
        24576, 12288, 192, 192,    // d2f             (t 8..11)
        24576, 12288, 192, 192,    // d2b             (t 12..15)
        16384, 128,                // dense           (t 16,17)
        3072, 24                   // out             (t 18,19)
    };

    WArgs a;
    int off = 0;
    for (int t = 0; t < 20; ++t) {
        a.src[t] = d_in[t + 3];
        a.off[t] = off;
        off += wc[t];
    }
    a.off[20] = off;                         // 122,904 elements

    const unsigned long long arena_bytes = 245952ull;
    const unsigned long long feat_bytes  = 4096ull * 128ull * 4ull;
    const unsigned long long seq_full    = 72ull * 4096ull * 128ull * 2ull;
    const unsigned long long fixed       = arena_bytes + feat_bytes;

    int nc = 32;
    for (int c = 1; c <= 32; c *= 2) {
        if (fixed + seq_full / (unsigned long long)c <= (unsigned long long)ws_size) { nc = c; break; }
    }
    const int bchunk = 4096 / nc;

    unsigned short* arena = (unsigned short*)d_ws;
    float* feat           = (float*)((char*)d_ws + arena_bytes);
    unsigned short* seq   = (unsigned short*)((char*)d_ws + fixed);

    convert_w<<<128, 256, 0, stream>>>(a, arena, (const unsigned short*)d_in[0]);

    const unsigned short* d1fW = arena + a.off[0];
    const unsigned short* d1fU = arena + a.off[1];
    const unsigned short* d1fbi= arena + a.off[2];
    const unsigned short* d1fbr= arena + a.off[3];
    const unsigned short* d1bW = arena + a.off[4];
    const unsigned short* d1bU = arena + a.off[5];
    const unsigned short* d1bbi= arena + a.off[6];
    const unsigned short* d1bbr= arena + a.off[7];
    const unsigned short* d2fW = arena + a.off[8];
    const unsigned short* d2fU = arena + a.off[9];
    const unsigned short* d2fbi= arena + a.off[10];
    const unsigned short* d2fbr= arena + a.off[11];
    const unsigned short* d2bW = arena + a.off[12];
    const unsigned short* d2bU = arena + a.off[13];
    const unsigned short* d2bbi= arena + a.off[14];
    const unsigned short* d2bbr= arena + a.off[15];
    const unsigned short* dW   = arena + a.off[16];
    const unsigned short* db   = arena + a.off[17];
    const unsigned short* oW   = arena + a.off[18];
    const unsigned short* ob   = arena + a.off[19];

    for (int c = 0; c < nc; ++c) {
        const int cb = c * bchunk;
        gru1_kernel<<<dim3(bchunk / 16, 2), 256, 0, stream>>>(
            d_in[0], d_in[1], d_in[2], cb, bchunk,
            d1fW, d1fU, d1fbi, d1fbr, d1bW, d1bU, d1bbi, d1bbr, seq);
        gru2_kernel<<<dim3(bchunk / 16, 2), 256, 0, stream>>>(
            seq, cb, bchunk,
            d2fW, d2fU, d2fbi, d2fbr, d2bW, d2bU, d2bbi, d2bbr, feat);
    }
    head_kernel<<<256, 256, 0, stream>>>(
        feat, dW, db, oW, ob, (float*)d_out);
}